// Round 8
// baseline (242.032 us; speedup 1.0000x reference)
//
#include <hip/hip_runtime.h>
#include <math.h>

#define BB 16
#define MM 32
#define NN 8400
#define NCC 80
#define RMM 16
#define EPSF 1e-7f
#define NCHUNK 33            // ceil(8400/256)
#define DBLOCKS 4200         // decode grid; phase1: 4 rounds exactly, phase2: 5 rounds
#define NPARTBLK (2 * BB * NCHUNK)   // 1056 assign_loss blocks

typedef unsigned long long ull;

// ---------------------------------------------------------------------------
// ws layout (floats):
//   pdbox   : 2*BB*NN*4   ([rb*NN+n][4])
//   lse     : 2*BB*NN*4
//   topk1   : BB*MM*10 (int)
//   topk2   : BB*MM    (int)
//   partial : NPARTBLK*8      (assign_loss per-block partials, q0..q4)
//   psp     : DBLOCKS*2       (softplus per-block partials, from decode)
//   counter : 1 uint          (last-block-done; zeroed by decode)
// ---------------------------------------------------------------------------

__device__ inline ull ullmax(ull a, ull b) { return a > b ? a : b; }
__device__ inline ull ullmin(ull a, ull b) { return a < b ? a : b; }

// Shared align-metric computation. __noinline__ => ONE codegen => bit-identical
// values in align_topk_kernel and assign_loss_kernel (assign's argmax must
// agree with topk's ordering on the same logical values).
__device__ __noinline__ float align_val(
    float px, float py, float pz, float pw,
    float g0, float g1, float g2, float g3, float x)
{
    float iw = fmaxf(fminf(pz, g2) - fmaxf(px, g0), 0.0f);
    float ih = fmaxf(fminf(pw, g3) - fmaxf(py, g1), 0.0f);
    float inter = iw * ih;
    float pa = (pz - px) * (pw - py);
    float ga = (g2 - g0) * (g3 - g1);
    float iou = inter / (pa + ga - inter + EPSF);
    float sig = __builtin_amdgcn_rcpf(1.0f + __expf(-x));
    float i2 = iou * iou;
    return sig * (i2 * i2 * i2);
}

__device__ inline float fast_softplus(float x) {
    float e = __expf(-fabsf(x));
    return fmaxf(x, 0.0f) + __logf(1.0f + e);
}

// ---- block reduce helper (result valid on thread 0) ------------------------
__device__ inline float blockReduceSum(float v, float* sh) {
    for (int o = 32; o > 0; o >>= 1) v += __shfl_down(v, o, 64);
    int lane = threadIdx.x & 63;
    int w = threadIdx.x >> 6;
    __syncthreads();
    if (lane == 0) sh[w] = v;
    __syncthreads();
    float r = 0.0f;
    if (threadIdx.x == 0) r = sh[0] + sh[1] + sh[2] + sh[3];
    return r;
}

// ---- kernel 1: decode (quad-cooperative softmax, batched loads) + softplus -
// All global loads of each phase are hoisted and issued back-to-back before
// any consumption: 4 (phase 1) + 5 (phase 2) independent loads in flight per
// thread — max memory-level parallelism test against the ~1.5 TB/s wall.
__global__ __launch_bounds__(256) void decode_kernel(
    const float* __restrict__ regs0, const float* __restrict__ regs1,
    const float* __restrict__ cls0, const float* __restrict__ cls1,
    const float* __restrict__ anchors, const float* __restrict__ strides,
    float* __restrict__ pdbox, float* __restrict__ lse,
    float* __restrict__ psp, unsigned* __restrict__ counter)
{
    int tid = threadIdx.x;
    int lane = tid & 63;
    if (blockIdx.x == 0 && tid == 0) *counter = 0u;   // for assign_loss last-block
    const size_t QSTR = (size_t)DBLOCKS * 256;      // 1,075,200 threads
    const size_t QPB  = (size_t)BB * NN * 16;       // float4 per branch (regs)
    size_t base = (size_t)blockIdx.x * 256 + tid;

    // ---- phase 1: batched loads ----
    float4 v[4];
#pragma unroll
    for (int r = 0; r < 4; ++r) {
        size_t Q = base + (size_t)r * QSTR;
        int br = Q >= QPB;
        const float4* src = (const float4*)(br ? regs1 : regs0);
        v[r] = src[Q - (br ? QPB : 0)];
    }

#pragma unroll
    for (int r = 0; r < 4; ++r) {
        size_t Q = base + (size_t)r * QSTR;
        int br = Q >= QPB;
        float4 w = v[r];

        float mx = fmaxf(fmaxf(w.x, w.y), fmaxf(w.z, w.w));
        mx = fmaxf(mx, __shfl_xor(mx, 1, 4));
        mx = fmaxf(mx, __shfl_xor(mx, 2, 4));

        int q = lane & 3;
        float w0 = (float)(q * 4);
        float e0 = __expf(w.x - mx), e1 = __expf(w.y - mx);
        float e2 = __expf(w.z - mx), e3 = __expf(w.w - mx);
        float se = e0 + e1 + e2 + e3;
        float sd = e0 * w0 + e1 * (w0 + 1.0f) + e2 * (w0 + 2.0f) + e3 * (w0 + 3.0f);
        se += __shfl_xor(se, 1, 4); se += __shfl_xor(se, 2, 4);
        sd += __shfl_xor(sd, 1, 4); sd += __shfl_xor(sd, 2, 4);

        float d = sd * __builtin_amdgcn_rcpf(se);
        float l = mx + __logf(se);

        int gb = lane & ~15;
        float d0 = __shfl(d, gb + 0),  d1 = __shfl(d, gb + 4);
        float d2 = __shfl(d, gb + 8),  d3 = __shfl(d, gb + 12);
        float l0 = __shfl(l, gb + 0),  l1 = __shfl(l, gb + 4);
        float l2 = __shfl(l, gb + 8),  l3 = __shfl(l, gb + 12);

        if ((lane & 15) == 0) {
            int A = (int)(Q >> 4);                  // global anchor index
            int bn = A - br * (BB * NN);
            int n = bn % NN;
            float ax = anchors[2 * n], ay = anchors[2 * n + 1];
            float st = strides[n];
            ((float4*)pdbox)[A] = make_float4(ax - d0 * st, ay - d1 * st,
                                              ax + d2 * st, ay + d3 * st);
            ((float4*)lse)[A] = make_float4(l0, l1, l2, l3);
        }
    }

    // ---- phase 2: softplus, batched loads (5 rounds exactly) ----
    const size_t half4 = (size_t)BB * NN * NCC / 4;   // 2,688,000 float4 per branch
    float4 c[5];
    int cb[5];
#pragma unroll
    for (int r = 0; r < 5; ++r) {
        size_t idx = base + (size_t)r * QSTR;
        int br = idx >= half4;
        cb[r] = br;
        c[r] = br ? ((const float4*)cls1)[idx - half4] : ((const float4*)cls0)[idx];
    }
    float s0 = 0.0f, s1 = 0.0f;
#pragma unroll
    for (int r = 0; r < 5; ++r) {
        float4 w = c[r];
        float s = fast_softplus(w.x) + fast_softplus(w.y) +
                  fast_softplus(w.z) + fast_softplus(w.w);
        if (cb[r]) s1 += s; else s0 += s;
    }
    __shared__ float sh[4];
    float r0 = blockReduceSum(s0, sh);
    __syncthreads();
    float r1 = blockReduceSum(s1, sh);
    if (tid == 0) {
        psp[blockIdx.x * 2 + 0] = r0;
        psp[blockIdx.x * 2 + 1] = r1;
    }
}

// ---- kernel 2: align + top-k via analytic in-box rectangle enumeration ----
// In-box anchors of gt [g0,g1,g2,g3] form a rectangle per anchor level
// (stride 8/16/32, grid 80/40/20). Enumerate rectangle candidates (widened
// +-1, re-tested with the EXACT reference float compares) plus candidates
// n=0..63 (reproduces lax.top_k zero-padding tie semantics; padding indices
// are provably within 0..63 since padding only occurs when <10 positives
// exist, leaving >=54 zero-align indices among 0..63). Rectangles skip n<64
// to avoid duplicates. key = (bits(al)<<32)|(NN-n): desc value, asc index.
__global__ __launch_bounds__(256) void align_topk_kernel(
    const float* __restrict__ cls0, const float* __restrict__ cls1,
    const int* __restrict__ gt_labels, const float* __restrict__ gt_bboxes,
    const float* __restrict__ pdbox,
    int* __restrict__ topk1, int* __restrict__ topk2)
{
    int r = blockIdx.x;                 // 0 .. 2*BB*MM-1
    int br = r / (BB * MM);
    int bm = r - br * (BB * MM);
    int b = bm / MM;
    int tid = threadIdx.x;

    const float* gt = gt_bboxes + (size_t)bm * 4;
    float g0 = gt[0], g1 = gt[1], g2 = gt[2], g3 = gt[3];
    int lab = gt_labels[bm];
    const float* clscol = (br == 0 ? cls0 : cls1) + (size_t)b * NN * NCC + lab;
    const float4* pb4 = (const float4*)pdbox + (size_t)(br * BB + b) * NN;

    const int lvl_s[3] = {8, 16, 32};
    const int lvl_g[3] = {80, 40, 20};
    const int lvl_b[3] = {0, 6400, 8000};

    ull loc[10];
#pragma unroll
    for (int j = 0; j < 10; ++j) loc[j] = 0ull;

    // fixed candidates n = 0..63 (level 0, gy=0, gx=n)
    if (tid < 64) {
        int n = tid;
        float ax = ((float)n + 0.5f) * 8.0f, ay = 4.0f;
        ull key = (ull)(unsigned)(NN - n);
        if (ax >= g0 && ax <= g2 && ay >= g1 && ay <= g3) {
            float4 pb = pb4[n];
            float x = clscol[(size_t)n * NCC];
            float al = align_val(pb.x, pb.y, pb.z, pb.w, g0, g1, g2, g3, x);
            key |= ((ull)__float_as_uint(al) << 32);
        }
#pragma unroll
        for (int j = 9; j >= 1; --j)
            loc[j] = ullmax(loc[j], ullmin(loc[j - 1], key));
        loc[0] = ullmax(loc[0], key);
    }

    // rectangle candidates per level
    for (int lvl = 0; lvl < 3; ++lvl) {
        int s = lvl_s[lvl], g = lvl_g[lvl], nb = lvl_b[lvl];
        float fs = (float)s;
        int x0 = (int)ceilf(g0 / fs - 0.5f) - 1; if (x0 < 0) x0 = 0;
        int x1 = (int)floorf(g2 / fs - 0.5f) + 1; if (x1 > g - 1) x1 = g - 1;
        int y0 = (int)ceilf(g1 / fs - 0.5f) - 1; if (y0 < 0) y0 = 0;
        int y1 = (int)floorf(g3 / fs - 0.5f) + 1; if (y1 > g - 1) y1 = g - 1;
        int rw = x1 - x0 + 1, rh = y1 - y0 + 1;
        if (rw <= 0 || rh <= 0) continue;
        int cnt = rw * rh;
        for (int c = tid; c < cnt; c += 256) {
            int gy = y0 + c / rw;
            int gx = x0 + c % rw;
            int n = nb + gy * g + gx;
            if (n < 64) continue;       // covered by fixed set
            float ax = ((float)gx + 0.5f) * fs;
            float ay = ((float)gy + 0.5f) * fs;
            if (!(ax >= g0 && ax <= g2 && ay >= g1 && ay <= g3)) continue;
            float4 pb = pb4[n];
            float x = clscol[(size_t)n * NCC];
            float al = align_val(pb.x, pb.y, pb.z, pb.w, g0, g1, g2, g3, x);
            ull key = ((ull)__float_as_uint(al) << 32) | (unsigned)(NN - n);
            if (key > loc[9]) {
#pragma unroll
                for (int j = 9; j >= 1; --j)
                    loc[j] = ullmax(loc[j], ullmin(loc[j - 1], key));
                loc[0] = ullmax(loc[0], key);
            }
        }
    }

    if (br == 1) {
        ull best = loc[0];
        for (int o = 32; o > 0; o >>= 1) best = ullmax(best, __shfl_down(best, o, 64));
        __shared__ ull sm[4];
        int lane = tid & 63, w = tid >> 6;
        if (lane == 0) sm[w] = best;
        __syncthreads();
        if (tid == 0) {
            best = ullmax(ullmax(sm[0], sm[1]), ullmax(sm[2], sm[3]));
            topk2[bm] = NN - (int)(best & 0xffffffffull);
        }
        return;
    }

    __shared__ ull ls[256 * 10];
#pragma unroll
    for (int j = 0; j < 10; ++j) ls[tid * 10 + j] = loc[j];
    __syncthreads();

    for (int s = 128; s > 0; s >>= 1) {
        if (tid < s) {
            ull* A = &ls[tid * 10];
            ull* B2 = &ls[(tid + s) * 10];
            ull o[10];
            int ia = 0, ib = 0;
#pragma unroll
            for (int j = 0; j < 10; ++j) {
                ull av = A[ia], bv = B2[ib];
                if (av >= bv) { o[j] = av; ++ia; }
                else          { o[j] = bv; ++ib; }
            }
#pragma unroll
            for (int j = 0; j < 10; ++j) A[j] = o[j];
        }
        __syncthreads();
    }
    if (tid < 10) topk1[bm * 10 + tid] = NN - (int)(ls[tid] & 0xffffffffull);
}

// ---- kernel 3: assignment + fg-only losses + (last block) finalize ---------
// grid: (NCHUNK, 2*BB); partial[(rb*NCHUNK+cx)*8+q], q: 0=sxt 1=box 2=dfl 3=nfg 4=mpos
__global__ __launch_bounds__(256) void assign_loss_kernel(
    const int* __restrict__ topk1, const int* __restrict__ topk2,
    const float* __restrict__ mask_gt,
    const int* __restrict__ gt_labels, const float* __restrict__ gt_bboxes,
    const float* __restrict__ cls0, const float* __restrict__ cls1,
    const float* __restrict__ regs0, const float* __restrict__ regs1,
    const float* __restrict__ anchors, const float* __restrict__ strides,
    const float* __restrict__ pdbox, const float* __restrict__ lse,
    float* __restrict__ partial, const float* __restrict__ psp,
    unsigned* __restrict__ counter, float* __restrict__ out)
{
    int cx = blockIdx.x;
    int rb = blockIdx.y;                 // branch*BB + b
    int br = rb / BB;
    int b = rb - br * BB;
    int tid = threadIdx.x;
    int n = cx * 256 + tid;

    __shared__ float g[MM * 4];
    __shared__ int gl[MM];
    __shared__ float gm[MM];
    __shared__ int tk[MM * 10];
    __shared__ int tk2s[MM];
    if (tid < MM * 4) g[tid] = gt_bboxes[b * MM * 4 + tid];
    if (tid < MM) {
        gl[tid] = gt_labels[b * MM + tid];
        gm[tid] = mask_gt[b * MM + tid];
        tk2s[tid] = topk2[b * MM + tid];
    }
    for (int j = tid; j < MM * 10; j += 256) tk[j] = topk1[b * MM * 10 + j];
    __syncthreads();

    const float* cls = (br == 0 ? cls0 : cls1);
    float sxt = 0.0f, sbox = 0.0f, sdfl = 0.0f, sfg = 0.0f, smp = 0.0f;

    if (n < NN) {
        const float* cp = cls + ((size_t)b * NN + n) * NCC;
        float2 anc = ((const float2*)anchors)[n];
        size_t i = (size_t)rb * NN + n;
        float4 pb = ((const float4*)pdbox)[i];

        // column argmax over m, align recomputed (bit-identical to topk's)
        float best = 0.0f;
        int mi = 0;
        for (int m = 0; m < MM; ++m) {
            float g0 = g[4 * m], g1 = g[4 * m + 1], g2 = g[4 * m + 2], g3 = g[4 * m + 3];
            if (anc.x >= g0 && anc.x <= g2 && anc.y >= g1 && anc.y <= g3) {
                float x = cp[gl[m]];
                float al = align_val(pb.x, pb.y, pb.z, pb.w, g0, g1, g2, g3, x);
                if (al > best) { best = al; mi = m; }
            }
        }

        int ind = 0;
        if (br == 0) {
            const int* tkp = &tk[mi * 10];
#pragma unroll
            for (int j = 0; j < 10; ++j)
                if (tkp[j] == n) ind = 1;
        } else {
            if (tk2s[mi] == n) ind = 1;
        }
        float mp = ind ? gm[mi] : 0.0f;
        smp = mp;
        if (mp > 0.0f) {
            sfg = 1.0f;
            float t0 = g[4 * mi] * mp, t1 = g[4 * mi + 1] * mp;
            float t2 = g[4 * mi + 2] * mp, t3 = g[4 * mi + 3] * mp;

            // plain IoU (for tscores)
            float iw = fmaxf(fminf(pb.z, t2) - fmaxf(pb.x, t0), 0.0f);
            float ih = fmaxf(fminf(pb.w, t3) - fmaxf(pb.y, t1), 0.0f);
            float inter = iw * ih;
            float w1 = pb.z - pb.x, h1 = pb.w - pb.y;
            float w2 = t2 - t0, h2 = t3 - t1;
            float uni = w1 * h1 + w2 * h2 - inter + EPSF;
            float iou = inter / uni;

            // -x*t term of BCE
            float x = cp[gl[mi]];
            sxt = x * iou;

            // CIoU (replicating reference's ch bug: ch = max(y2) - b1y1)
            float cw = fmaxf(pb.z, t2) - fminf(pb.x, t0);
            float ch = fmaxf(pb.w, t3) - pb.y;     // BUG in reference, replicated
            float c2 = cw * cw + ch * ch + EPSF;
            float dx = pb.x + pb.z - t0 - t2;
            float dy = pb.y + pb.w - t1 - t3;
            float rho2 = (dx * dx + dy * dy) * 0.25f;
            float dat = atanf(w2 / (h2 + EPSF)) - atanf(w1 / (h1 + EPSF));
            float v = 0.40528473f * dat * dat;     // 4/pi^2
            float alpha_ = v / (v - iou + 1.0000001f);
            float ciou = iou - (rho2 / c2 + v * alpha_);
            sbox = 1.0f - ciou;

            // DFL
            float st = strides[n];
            float tb[4] = {(anc.x - t0) / st, (anc.y - t1) / st,
                           (t2 - anc.x) / st, (t3 - anc.y) / st};
            float4 l4 = ((const float4*)lse)[i];
            float lv[4] = {l4.x, l4.y, l4.z, l4.w};
            const float* regs = (br == 0 ? regs0 : regs1) + ((size_t)b * NN + n) * 64;
            float dsum = 0.0f;
#pragma unroll
            for (int s2 = 0; s2 < 4; ++s2) {
                float t = fminf(fmaxf(tb[s2], 0.0f), (float)RMM - 1.01f);
                int tl = (int)t;
                float wl = (float)(tl + 1) - t;
                float wr = 1.0f - wl;
                float lp_l = regs[s2 * 16 + tl] - lv[s2];
                float lp_r = regs[s2 * 16 + tl + 1] - lv[s2];
                dsum += -(lp_l * wl + lp_r * wr);
            }
            sdfl = dsum;
        }
    }

    __shared__ float sh[4];
    float vals[5] = {sxt, sbox, sdfl, sfg, smp};
    float* outp = partial + ((size_t)rb * NCHUNK + cx) * 8;
#pragma unroll
    for (int q = 0; q < 5; ++q) {
        float r = blockReduceSum(vals[q], sh);
        if (tid == 0) outp[q] = r;
        __syncthreads();
    }

    // ---- last-block-done finalize ----
    __shared__ int islast;
    if (tid == 0) {
        __threadfence();
        unsigned t = atomicAdd(counter, 1u);
        islast = (t == NPARTBLK - 1);
    }
    __syncthreads();
    if (!islast) return;
    __threadfence();

    float s[10];
#pragma unroll
    for (int j = 0; j < 10; ++j) s[j] = 0.0f;
    for (int blk = tid; blk < NPARTBLK; blk += 256) {
        int brq = blk / (BB * NCHUNK);
#pragma unroll
        for (int q = 0; q < 5; ++q) s[brq * 5 + q] += partial[(size_t)blk * 8 + q];
    }
    float sp0 = 0.0f, sp1 = 0.0f;
    for (int i2 = tid; i2 < DBLOCKS; i2 += 256) {
        sp0 += psp[2 * i2];
        sp1 += psp[2 * i2 + 1];
    }

    __shared__ float res[12];
#pragma unroll
    for (int j = 0; j < 10; ++j) {
        float r = blockReduceSum(s[j], sh);
        if (tid == 0) res[j] = r;
        __syncthreads();
    }
    {
        float r = blockReduceSum(sp0, sh);
        if (tid == 0) res[10] = r;
        __syncthreads();
        r = blockReduceSum(sp1, sh);
        if (tid == 0) res[11] = r;
        __syncthreads();
    }

    if (tid == 0) {
        float t[2], cc[2], bx[2], df[2];
        for (int brq = 0; brq < 2; ++brq) {
            float a0 = res[brq * 5 + 0], a1 = res[brq * 5 + 1], a2 = res[brq * 5 + 2];
            float a3 = res[brq * 5 + 3], a4 = res[brq * 5 + 4];
            float sp = res[10 + brq];
            float nfg = fmaxf(a3, 1.0f);
            float lcls = (sp - a0) / fmaxf(a4, 1.0f);
            float lbox = a1 / nfg;
            float ldfl = a2 / (nfg * 4.0f);
            t[brq] = lcls * 1.0f + lbox * 7.5f + ldfl * 1.5f;
            cc[brq] = lcls;
            bx[brq] = lbox;
            df[brq] = ldfl;
        }
        out[0] = t[0] + t[1];
        out[1] = cc[0] + cc[1];
        out[2] = bx[0] + bx[1];
        out[3] = df[0] + df[1];
        out[4] = t[0];
        out[5] = t[1];
    }
}

// ---------------------------------------------------------------------------
extern "C" void kernel_launch(void* const* d_in, const int* in_sizes, int n_in,
                              void* d_out, int out_size, void* d_ws, size_t ws_size,
                              hipStream_t stream) {
    const float* cls0    = (const float*)d_in[0];  // cls_scores
    const float* regs0   = (const float*)d_in[1];  // box_regs
    const float* cls1    = (const float*)d_in[2];  // one2one_cls
    const float* regs1   = (const float*)d_in[3];  // one2one_reg
    const float* anchors = (const float*)d_in[4];
    const float* strides = (const float*)d_in[5];
    const int*   gt_labels = (const int*)d_in[6];
    const float* gt_bboxes = (const float*)d_in[7];
    const float* mask_gt   = (const float*)d_in[8];
    float* out = (float*)d_out;

    float* pdbox   = (float*)d_ws;                       // 2*BB*NN*4
    float* lse     = pdbox + (size_t)2 * BB * NN * 4;    // 2*BB*NN*4
    int*   topk1   = (int*)(lse + (size_t)2 * BB * NN * 4);  // BB*MM*10
    int*   topk2   = topk1 + BB * MM * 10;               // BB*MM
    float* partial = (float*)(topk2 + BB * MM);          // NPARTBLK*8
    float* psp     = partial + (size_t)NPARTBLK * 8;     // DBLOCKS*2
    unsigned* counter = (unsigned*)(psp + (size_t)DBLOCKS * 2);

    decode_kernel<<<DBLOCKS, 256, 0, stream>>>(
        regs0, regs1, cls0, cls1, anchors, strides, pdbox, lse, psp, counter);

    align_topk_kernel<<<2 * BB * MM, 256, 0, stream>>>(
        cls0, cls1, gt_labels, gt_bboxes, pdbox, topk1, topk2);

    dim3 agrid(NCHUNK, 2 * BB);
    assign_loss_kernel<<<agrid, 256, 0, stream>>>(
        topk1, topk2, mask_gt, gt_labels, gt_bboxes,
        cls0, cls1, regs0, regs1, anchors, strides, pdbox, lse,
        partial, psp, counter, out);
}